// Round 6
// baseline (214.302 us; speedup 1.0000x reference)
//
#include <hip/hip_runtime.h>
#include <hip/hip_bf16.h>

// BatchSplitFF: DM=1024, NEXPERTS=32, SETS=4 (ES=128 pairs), ESIZE=32, B=2, S=8192
#define DM   1024
#define NES  128
#define GT   32
#define NGRP 512
#define FSZ  32

typedef float f32x4 __attribute__((ext_vector_type(4)));
typedef short s16x8 __attribute__((ext_vector_type(8)));

// async global->LDS, 16B per lane; LDS dest must be wave-uniform base.
#define GL2LDS(gp, lp) __builtin_amdgcn_global_load_lds(                      \
    (const __attribute__((address_space(1))) void*)(gp),                     \
    (__attribute__((address_space(3))) void*)(lp), 16, 0, 0)

__device__ inline unsigned short f2bf(float f) {   // RNE f32->bf16
  union { float f; unsigned int u; } x; x.f = f;
  unsigned int r = x.u + 0x7fffu + ((x.u >> 16) & 1u);
  return (unsigned short)(r >> 16);
}
__device__ inline float bf2f(unsigned short h) {
  union { unsigned int u; float f; } x; x.u = ((unsigned int)h) << 16;
  return x.f;
}

// ---------------------------------------------------------------------------
// Kernel A: controller logits (f32) + argmax mask + x->bf16 emission.
// v3: async double-buffered staging (global_load_lds, 32-dd sub-chunks, one
// barrier/chunk, loads in flight across compute). Per-output fmaf chain is
// BIT-IDENTICAL to rounds 1-5: part[] flushed at 64-dd boundaries.
// LDS 40KB (lg aliases wcs buf0, which is dead after the last compute).
// ---------------------------------------------------------------------------
__global__ __launch_bounds__(256, 2) void kA(const float* __restrict__ x,
                                             const float* __restrict__ Wc,
                                             const float* __restrict__ bc,
                                             unsigned int* __restrict__ sel,
                                             unsigned short* __restrict__ xb) {
  __shared__ float smem[10240];                    // 40 KB
  float* const wcsA = smem;                        // [32dd][128es]
  float* const wcsB = smem + 4096;
  float* const xsA  = smem + 8192;                 // [32t][32dd]
  float* const xsB  = smem + 9216;
  float* const lg   = smem;                        // alias wcsA (epilogue only)
  const int g   = blockIdx.x;
  const int tid = threadIdx.x;
  const int l   = tid & 63, w = tid >> 6;
  const int es0 = (tid & 31) * 4;
  const int t0  = (tid >> 5) * 4;
  const float* xg = x + (size_t)g * GT * DM;

  float acc[16], part[16];
#pragma unroll
  for (int i = 0; i < 16; ++i) acc[i] = 0.f;

  // stage 32-dd sub-chunk c into buffer b: wcs 16KB (4 insts/wave) + xs 4KB (1)
  auto STAGE = [&](int c, float* wdst, float* xdst) {
    const int d0 = c * 32;
#pragma unroll
    for (int kk = 0; kk < 4; ++kk) {
      int e4 = w * 1024 + kk * 256 + l * 4;        // f32 index in chunk
      GL2LDS(Wc + (size_t)(d0 + (e4 >> 7)) * NES + (e4 & 127),
             wdst + w * 1024 + kk * 256);          // uniform base per wave
    }
    int ex = w * 256 + l * 4;
    GL2LDS(xg + (size_t)(ex >> 5) * DM + d0 + (ex & 31), xdst + w * 256);
  };

  STAGE(0, wcsA, xsA);
  asm volatile("s_waitcnt vmcnt(0)" ::: "memory");
  __syncthreads();

  for (int c = 0; c < 32; ++c) {
    const int b = c & 1;
    const float* wp = b ? wcsB : wcsA;
    const float* xp = b ? xsB : xsA;
    if (c < 31) STAGE(c + 1, b ? wcsA : wcsB, b ? xsA : xsB);

    {   // emit bf16 x chunk: 4 elems/thread (fused former kXB)
      int idx = tid * 4;
      float4 a4 = *(const float4*)&xp[idx];
      short4 v;
      v.x = (short)f2bf(a4.x); v.y = (short)f2bf(a4.y);
      v.z = (short)f2bf(a4.z); v.w = (short)f2bf(a4.w);
      *(short4*)&xb[((size_t)g * GT + (idx >> 5)) * DM + c * 32 + (idx & 31)] = v;
    }

    if ((c & 1) == 0) {
#pragma unroll
      for (int i = 0; i < 16; ++i) part[i] = 0.f;   // 64-dd boundary: flush
    }
#pragma unroll 2
    for (int dd = 0; dd < 32; dd += 4) {
      float4 w0 = *(const float4*)&wp[(dd + 0) * NES + es0];
      float4 w1 = *(const float4*)&wp[(dd + 1) * NES + es0];
      float4 w2 = *(const float4*)&wp[(dd + 2) * NES + es0];
      float4 w3 = *(const float4*)&wp[(dd + 3) * NES + es0];
      float4 xv0 = *(const float4*)&xp[(t0 + 0) * 32 + dd];
      float4 xv1 = *(const float4*)&xp[(t0 + 1) * 32 + dd];
      float4 xv2 = *(const float4*)&xp[(t0 + 2) * 32 + dd];
      float4 xv3 = *(const float4*)&xp[(t0 + 3) * 32 + dd];
#define KSTEP(i, XV)                                                       \
      part[i*4+0] = fmaf(XV.x, w0.x, part[i*4+0]);                         \
      part[i*4+1] = fmaf(XV.x, w0.y, part[i*4+1]);                         \
      part[i*4+2] = fmaf(XV.x, w0.z, part[i*4+2]);                         \
      part[i*4+3] = fmaf(XV.x, w0.w, part[i*4+3]);                         \
      part[i*4+0] = fmaf(XV.y, w1.x, part[i*4+0]);                         \
      part[i*4+1] = fmaf(XV.y, w1.y, part[i*4+1]);                         \
      part[i*4+2] = fmaf(XV.y, w1.z, part[i*4+2]);                         \
      part[i*4+3] = fmaf(XV.y, w1.w, part[i*4+3]);                         \
      part[i*4+0] = fmaf(XV.z, w2.x, part[i*4+0]);                         \
      part[i*4+1] = fmaf(XV.z, w2.y, part[i*4+1]);                         \
      part[i*4+2] = fmaf(XV.z, w2.z, part[i*4+2]);                         \
      part[i*4+3] = fmaf(XV.z, w2.w, part[i*4+3]);                         \
      part[i*4+0] = fmaf(XV.w, w3.x, part[i*4+0]);                         \
      part[i*4+1] = fmaf(XV.w, w3.y, part[i*4+1]);                         \
      part[i*4+2] = fmaf(XV.w, w3.z, part[i*4+2]);                         \
      part[i*4+3] = fmaf(XV.w, w3.w, part[i*4+3]);
      KSTEP(0, xv0) KSTEP(1, xv1) KSTEP(2, xv2) KSTEP(3, xv3)
#undef KSTEP
    }
    if (c & 1) {
#pragma unroll
      for (int i = 0; i < 16; ++i) acc[i] += part[i];
    }
    asm volatile("s_waitcnt vmcnt(0)" ::: "memory");
    __syncthreads();                               // chunk c+1 resident
  }

  // epilogue (unchanged numerics); lg aliases wcsA — all compute is done.
#pragma unroll
  for (int i = 0; i < 4; ++i) {
    int t = t0 + i;
    float tie = (float)((double)t * (1e-6 / 31.0));
#pragma unroll
    for (int j = 0; j < 4; ++j) {
      int es = es0 + j;
      lg[t * NES + es] = (acc[i * 4 + j] + bc[es]) + tie;
    }
  }
  __syncthreads();
  if (tid < NES) {
    float m = -INFINITY;
    for (int t = 0; t < GT; ++t) m = fmaxf(m, lg[t * NES + tid]);
    unsigned int msk = 0u;
    for (int t = 0; t < GT; ++t) if (lg[t * NES + tid] == m) msk |= (1u << t);
    sel[(size_t)g * NES + tid] = msk;
  }
}

// ---------------------------------------------------------------------------
// kW: merged weight repack (one launch). Blocks [0,2048): W1 -> bf16 B-frag
// (K=d, N=f). Blocks [2048,4096): W2 -> bf16 B-frag (K=f, N=d).
// ---------------------------------------------------------------------------
__global__ __launch_bounds__(256) void kW(const float* __restrict__ W1,
                                          const float* __restrict__ W2,
                                          unsigned short* __restrict__ W1f,
                                          unsigned short* __restrict__ W2f) {
  const int bid = blockIdx.x;
  if (bid < 2048) {
    int idx = bid * 256 + threadIdx.x;             // (es, kt, nh, lane)
    int l = idx & 63, nh = (idx >> 6) & 1, kt = (idx >> 7) & 31, es = idx >> 12;
    const float* src = W1 + ((size_t)es * DM + kt * 32 + (l >> 4) * 8) * FSZ
                          + nh * 16 + (l & 15);
    s16x8 v;
#pragma unroll
    for (int i = 0; i < 8; ++i) v[i] = (short)f2bf(src[(size_t)i * FSZ]);
    *(s16x8*)(W1f + (size_t)idx * 8) = v;
  } else {
    int idx = (bid - 2048) * 256 + threadIdx.x;    // (es, dt, lane)
    int l = idx & 63, dt = (idx >> 6) & 63, es = idx >> 12;
    const float* src = W2 + ((size_t)es * DM + dt * 16 + (l & 15)) * FSZ + (l >> 4) * 8;
    float4 a = *(const float4*)src;
    float4 b = *(const float4*)(src + 4);
    s16x8 v;
    v[0] = (short)f2bf(a.x); v[1] = (short)f2bf(a.y);
    v[2] = (short)f2bf(a.z); v[3] = (short)f2bf(a.w);
    v[4] = (short)f2bf(b.x); v[5] = (short)f2bf(b.y);
    v[6] = (short)f2bf(b.z); v[7] = (short)f2bf(b.w);
    *(s16x8*)(W2f + (size_t)idx * 8) = v;
  }
}

// ---------------------------------------------------------------------------
// kBm: inner = relu(xsel . W1[es] + b1[es]) via MFMA (unchanged from r4/r5).
// ---------------------------------------------------------------------------
__global__ __launch_bounds__(256, 2) void kBm(const unsigned short* __restrict__ xb,
                                              const unsigned short* __restrict__ W1f,
                                              const float* __restrict__ b1,
                                              const unsigned int* __restrict__ sel,
                                              unsigned short* __restrict__ innerb) {
  __shared__ unsigned short As[128 * 128];   // [row][k] bf16, byte^((row&7)<<4)
  __shared__ int tokL[128];
  __shared__ unsigned int mulL[128];
  const int bid = blockIdx.x;
  const int es = bid >> 2, g0 = (bid & 3) * 128;
  const int tid = threadIdx.x;
  const int l = tid & 63, w = tid >> 6;
  const int r15 = l & 15, q = l >> 4;
  const int mw = w * 32;

  if (tid < 128) {
    unsigned int m = sel[(size_t)(g0 + tid) * NES + es];
    tokL[tid] = (g0 + tid) * GT + (__ffs(m) - 1);
    mulL[tid] = (m & (m - 1)) ? m : 0u;
  }

  const int r = tid >> 1, p = tid & 1;
  const int swz = (r & 7) << 4;
  const unsigned int dbase = (unsigned int)r * 256 + (unsigned int)p * 128;

  f32x4 acc[2][2];
#pragma unroll
  for (int i = 0; i < 2; ++i)
#pragma unroll
    for (int j = 0; j < 2; ++j) acc[i][j] = (f32x4){0.f, 0.f, 0.f, 0.f};

  for (int c = 0; c < 8; ++c) {
    __syncthreads();
    unsigned int mm = mulL[r];
    if (!mm) {
      const unsigned short* src = xb + (size_t)tokL[r] * DM + c * 128 + p * 64;
#pragma unroll
      for (int j = 0; j < 8; ++j) {
        s16x8 v = *(const s16x8*)(src + j * 8);
        *(s16x8*)((char*)As + ((dbase + j * 16) ^ swz)) = v;
      }
    } else {
      size_t grow = (size_t)(g0 + r) * GT;
#pragma unroll
      for (int j = 0; j < 8; ++j) {
        float av[8] = {0.f, 0.f, 0.f, 0.f, 0.f, 0.f, 0.f, 0.f};
        unsigned int m2 = mm;
        while (m2) {
          int tt = __ffs(m2) - 1; m2 &= m2 - 1;
          s16x8 v = *(const s16x8*)(xb + (grow + tt) * DM + c * 128 + p * 64 + j * 8);
#pragma unroll
          for (int k = 0; k < 8; ++k) av[k] += bf2f((unsigned short)v[k]);
        }
        s16x8 o;
#pragma unroll
        for (int k = 0; k < 8; ++k) o[k] = (short)f2bf(av[k]);
        *(s16x8*)((char*)As + ((dbase + j * 16) ^ swz)) = o;
      }
    }
    __syncthreads();

#pragma unroll
    for (int s = 0; s < 4; ++s) {
      const int ks = c * 4 + s;
      const unsigned short* bp = W1f + ((size_t)es * 32 + ks) * 1024 + l * 8;
      s16x8 bf0 = *(const s16x8*)bp;
      s16x8 bf1 = *(const s16x8*)(bp + 512);
      const int row0 = mw + r15, row1 = mw + 16 + r15;
      s16x8 a0 = *(const s16x8*)((char*)As +
                   (((unsigned)row0 * 256 + s * 64 + q * 16) ^ ((row0 & 7) << 4)));
      s16x8 a1 = *(const s16x8*)((char*)As +
                   (((unsigned)row1 * 256 + s * 64 + q * 16) ^ ((row1 & 7) << 4)));
      acc[0][0] = __builtin_amdgcn_mfma_f32_16x16x32_bf16(a0, bf0, acc[0][0], 0, 0, 0);
      acc[0][1] = __builtin_amdgcn_mfma_f32_16x16x32_bf16(a0, bf1, acc[0][1], 0, 0, 0);
      acc[1][0] = __builtin_amdgcn_mfma_f32_16x16x32_bf16(a1, bf0, acc[1][0], 0, 0, 0);
      acc[1][1] = __builtin_amdgcn_mfma_f32_16x16x32_bf16(a1, bf1, acc[1][1], 0, 0, 0);
    }
  }

  float bia0 = b1[es * FSZ + r15];
  float bia1 = b1[es * FSZ + 16 + r15];
#pragma unroll
  for (int i = 0; i < 2; ++i)
#pragma unroll
    for (int rr = 0; rr < 4; ++rr) {
      int g = g0 + mw + i * 16 + q * 4 + rr;
      unsigned short* op = innerb + ((size_t)es * NGRP + g) * FSZ;
      op[r15]      = f2bf(fmaxf(acc[i][0][rr] + bia0, 0.f));
      op[16 + r15] = f2bf(fmaxf(acc[i][1][rr] + bia1, 0.f));
    }
}

// ---------------------------------------------------------------------------
// kC1: per-es dense GEMM (512g x 32f).(32f x 1024d) -> Rb bf16 [g][Ec][d],
// b2 folded (unchanged).
// ---------------------------------------------------------------------------
__global__ __launch_bounds__(256) void kC1(const unsigned short* __restrict__ innerb,
                                           const unsigned short* __restrict__ W2f,
                                           const float* __restrict__ b2,
                                           unsigned short* __restrict__ Rb,
                                           int es0, int Ec) {
  const int bid = blockIdx.x;
  const int esl = bid >> 5;
  const int es  = es0 + esl;
  const int mt  = (bid >> 3) & 3;
  const int nt  = bid & 7;
  const int tid = threadIdx.x;
  const int l = tid & 63, w = tid >> 6;
  const int r15 = l & 15, q = l >> 4;
  const int g0 = mt * 128 + (w >> 1) * 64;
  const int n0 = nt * 128 + (w & 1) * 64;

  const unsigned short* Ab = innerb + ((size_t)es * NGRP + g0 + r15) * FSZ + q * 8;
  const unsigned short* Bb = W2f + (((size_t)es * 64 + (n0 >> 4)) * 64 + l) * 8;
  s16x8 a[4], b[4];
#pragma unroll
  for (int i = 0; i < 4; ++i) a[i] = *(const s16x8*)(Ab + (size_t)i * 16 * FSZ);
#pragma unroll
  for (int j = 0; j < 4; ++j) b[j] = *(const s16x8*)(Bb + (size_t)j * 64 * 8);

  const f32x4 z = {0.f, 0.f, 0.f, 0.f};
  f32x4 acc[4][4];
#pragma unroll
  for (int i = 0; i < 4; ++i)
#pragma unroll
    for (int j = 0; j < 4; ++j)
      acc[i][j] = __builtin_amdgcn_mfma_f32_16x16x32_bf16(a[i], b[j], z, 0, 0, 0);

#pragma unroll
  for (int j = 0; j < 4; ++j) {
    const int col = n0 + j * 16 + r15;
    const float b2v = b2[(size_t)es * DM + col];
#pragma unroll
    for (int i = 0; i < 4; ++i) {
#pragma unroll
      for (int r = 0; r < 4; ++r) {
        const int g = g0 + i * 16 + q * 4 + r;
        Rb[((size_t)g * Ec + esl) * DM + col] = f2bf(acc[i][j][r] + b2v);
      }
    }
  }
}

// ---------------------------------------------------------------------------
// kC2: per-(group, d-quarter) gather-combine (unchanged from r5).
// ---------------------------------------------------------------------------
__global__ __launch_bounds__(256) void kC2(const unsigned short* __restrict__ Rb,
                                           const unsigned int* __restrict__ sel,
                                           float* __restrict__ out,
                                           int es0, int Ec, int direct) {
  __shared__ unsigned int cnt[32];
  __shared__ unsigned char list[32][128];
  const int bid = blockIdx.x;
  const int g = bid >> 2, dq = bid & 3;
  const int tid = threadIdx.x;
  if (tid < 32) cnt[tid] = 0;
  __syncthreads();
  if (tid < Ec) {
    unsigned int m = sel[(size_t)g * NES + es0 + tid];
    while (m) { int t = __ffs(m) - 1; m &= m - 1;
      unsigned int p = atomicAdd(&cnt[t], 1u);
      list[t][p] = (unsigned char)tid; }
  }
  __syncthreads();
  const int t = tid >> 3, part = tid & 7;
  const int d0 = dq * 256 + part * 32;
  const int n = (int)cnt[t];
  const unsigned short* base = Rb + (size_t)g * Ec * DM + d0;

  float acc[32];
#pragma unroll
  for (int i = 0; i < 32; ++i) acc[i] = 0.f;

  s16x8 cur[4];
  if (n) {
    const unsigned short* r = base + (size_t)list[t][0] * DM;
#pragma unroll
    for (int v = 0; v < 4; ++v) cur[v] = *(const s16x8*)(r + v * 8);
  }
  for (int e = 0; e < n; ++e) {
    s16x8 nxt[4];
    const bool more = (e + 1 < n);
    if (more) {
      const unsigned short* r = base + (size_t)list[t][e + 1] * DM;
#pragma unroll
      for (int v = 0; v < 4; ++v) nxt[v] = *(const s16x8*)(r + v * 8);
    }
#pragma unroll
    for (int v = 0; v < 4; ++v)
#pragma unroll
      for (int k = 0; k < 8; ++k)
        acc[v * 8 + k] += bf2f((unsigned short)cur[v][k]);
    if (more) {
#pragma unroll
      for (int v = 0; v < 4; ++v) cur[v] = nxt[v];
    }
  }

  float* op = out + ((size_t)g * GT + t) * DM + d0;
  if (direct) {
#pragma unroll
    for (int v = 0; v < 8; ++v)
      *(float4*)&op[v * 4] =
          make_float4(acc[v * 4], acc[v * 4 + 1], acc[v * 4 + 2], acc[v * 4 + 3]);
  } else {
#pragma unroll
    for (int v = 0; v < 8; ++v) {
      float4 o = *(float4*)&op[v * 4];
      o.x += acc[v * 4]; o.y += acc[v * 4 + 1];
      o.z += acc[v * 4 + 2]; o.w += acc[v * 4 + 3];
      *(float4*)&op[v * 4] = o;
    }
  }
}

extern "C" void kernel_launch(void* const* d_in, const int* in_sizes, int n_in,
                              void* d_out, int out_size, void* d_ws, size_t ws_size,
                              hipStream_t stream) {
  const float* x  = (const float*)d_in[0];
  const float* Wc = (const float*)d_in[1];
  const float* bc = (const float*)d_in[2];
  const float* W1 = (const float*)d_in[3];
  const float* b1 = (const float*)d_in[4];
  const float* W2 = (const float*)d_in[5];
  const float* b2 = (const float*)d_in[6];
  float* out = (float*)d_out;

  // ws: sel @0 (256 KB); innerb @1M (4 MB); W2f @6M (8.4 MB);
  //     W1f @15M (8.4 MB, dead after kBm); xb @24M (33.5 MB, dead after kBm);
  //     Rb @15M overlapping W1f+xb (sequential stream => safe).
  unsigned int* sel = (unsigned int*)d_ws;
  unsigned short* innerb = (unsigned short*)((char*)d_ws + (1u << 20));
  unsigned short* W2f = (unsigned short*)((char*)d_ws + (6u << 20));
  unsigned short* W1f = (unsigned short*)((char*)d_ws + (15u << 20));
  unsigned short* xb  = (unsigned short*)((char*)d_ws + (24u << 20));
  unsigned short* Rb  = (unsigned short*)((char*)d_ws + (15u << 20));

  int Ec = 128;
  while (Ec > 1 && (15u << 20) + (size_t)NGRP * Ec * DM * 2 > ws_size) Ec >>= 1;
  const int NC = NES / Ec;

  if (NC > 1)
    hipMemsetAsync(d_out, 0, (size_t)out_size * sizeof(float), stream);
  kA<<<NGRP, 256, 0, stream>>>(x, Wc, bc, sel, xb);
  kW<<<4096, 256, 0, stream>>>(W1, W2, W1f, W2f);
  kBm<<<NGRP, 256, 0, stream>>>(xb, W1f, b1, sel, innerb);
  for (int c = 0; c < NC; ++c) {
    kC1<<<Ec * 32, 256, 0, stream>>>(innerb, W2f, b2, Rb, c * Ec, Ec);
    kC2<<<NGRP * 4, 256, 0, stream>>>(Rb, sel, out, c * Ec, Ec, NC == 1);
  }
}